// Round 13
// baseline (931.608 us; speedup 1.0000x reference)
//
#include <hip/hip_runtime.h>

#define NN   50000
#define NNP  50048            // 1564 * 32 (padded M for reps tiles)
#define NE   262144
#define NOCP 32768
#define EAVA (NE - NOCP)      // 229376 = 7 * 32768
#define NG   64
#define HD   128
#define CAP  48
#define CHNK 32768

typedef _Float16 f16x8 __attribute__((ext_vector_type(8)));
typedef _Float16 f16x2 __attribute__((ext_vector_type(2)));
typedef float f32x4 __attribute__((ext_vector_type(4)));

// counted vmcnt waits
#define WAITVM12() asm volatile("s_waitcnt vmcnt(12)" ::: "memory")
#define WAITVM6()  asm volatile("s_waitcnt vmcnt(6)" ::: "memory")
#define WAITVM4()  asm volatile("s_waitcnt vmcnt(4)" ::: "memory")
#define WAITVM0()  asm volatile("s_waitcnt vmcnt(0)" ::: "memory")

__device__ __forceinline__ float elu_f(float v) { return v > 0.f ? v : (expf(v) - 1.f); }

__device__ __forceinline__ unsigned fenc(float f) {
  unsigned u = __float_as_uint(f);
  return (u & 0x80000000u) ? ~u : (u | 0x80000000u);
}
__device__ __forceinline__ float fdec(unsigned u) {
  return __uint_as_float((u & 0x80000000u) ? (u & 0x7fffffffu) : ~u);
}

// async global->LDS 16B per lane; LDS dst = base + lane*16 (wave-uniform base)
__device__ __forceinline__ void dma16(const void* g, void* l) {
  __builtin_amdgcn_global_load_lds((const __attribute__((address_space(1))) unsigned int*)g,
                                   (__attribute__((address_space(3))) unsigned int*)l,
                                   16, 0, 0);
}

__global__ __launch_bounds__(256) void zero_i(int* __restrict__ p, int n) {
  for (int i = blockIdx.x * 256 + threadIdx.x; i < n; i += gridDim.x * 256) p[i] = 0;
}

__global__ void init_small(unsigned* mx_enc, float* denom, unsigned* pmax_enc, int* amin) {
  int t = threadIdx.x;
  if (t < NG) { mx_enc[t] = 0u; denom[t] = 0.f; pmax_enc[t] = 0u; amin[t] = EAVA; }
}

// zero padding rows NN..NNP-1 of the 6 split arrays (one contiguous block)
__global__ __launch_bounds__(256) void zero_tails(_Float16* __restrict__ base) {
  int t = blockIdx.x * 256 + threadIdx.x;           // 6 arrays * 768 f16x8
  if (t >= 6 * 768) return;
  int arr = t / 768, off = t % 768;
  f16x8 z = {};
  *(f16x8*)(base + (size_t)arr * NNP * HD + (size_t)NN * HD + (size_t)off * 8) = z;
}

// ---------------- GNN aggregation (bucket-then-gather) ----------------
__global__ __launch_bounds__(256) void bucket_kernel(const int* __restrict__ ei,
    int* __restrict__ cnt, int* __restrict__ bucket) {
  int e = blockIdx.x * 256 + threadIdx.x;
  if (e >= NE) return;
  int dst = ei[NE + e];
  int src = ei[e];
  int slot = atomicAdd(&cnt[dst], 1);
  if (slot < CAP)
    bucket[(size_t)dst * CAP + slot] = (int)((unsigned)src | (e < NOCP ? 0x80000000u : 0u));
}

// gather: 4-wide unrolled, fp32 accumulate, emit split hi/lo fp16 (verified rounds 5-12)
__global__ __launch_bounds__(256) void gather_kernel(const float* __restrict__ x,
    const int* __restrict__ cnt, const int* __restrict__ bucket,
    _Float16* __restrict__ xsah, _Float16* __restrict__ xsal,
    _Float16* __restrict__ xsoh, _Float16* __restrict__ xsol) {
  int n = blockIdx.x * 4 + (threadIdx.x >> 6);
  if (n >= NN) return;
  int lane = threadIdx.x & 63;
  int c = cnt[n];
  if (c > CAP) c = CAP;
  float2 aall = make_float2(0.f, 0.f), aocp = aall;
  const int* bk = bucket + (size_t)n * CAP;
  for (int i0 = 0; i0 < c; i0 += 4) {
    int4 pk = *(const int4*)(bk + i0);
    bool m1 = (i0 + 1 < c), m2 = (i0 + 2 < c), m3 = (i0 + 3 < c);
    int r0 = pk.x & 0x7fffffff;
    int r1 = m1 ? (pk.y & 0x7fffffff) : 0;
    int r2 = m2 ? (pk.z & 0x7fffffff) : 0;
    int r3 = m3 ? (pk.w & 0x7fffffff) : 0;
    float2 v0 = *(const float2*)(x + (size_t)r0 * HD + lane * 2);
    float2 v1 = *(const float2*)(x + (size_t)r1 * HD + lane * 2);
    float2 v2 = *(const float2*)(x + (size_t)r2 * HD + lane * 2);
    float2 v3 = *(const float2*)(x + (size_t)r3 * HD + lane * 2);
    aall.x += v0.x; aall.y += v0.y;
    if (pk.x < 0) { aocp.x += v0.x; aocp.y += v0.y; }
    if (m1) { aall.x += v1.x; aall.y += v1.y; if (pk.y < 0) { aocp.x += v1.x; aocp.y += v1.y; } }
    if (m2) { aall.x += v2.x; aall.y += v2.y; if (pk.z < 0) { aocp.x += v2.x; aocp.y += v2.y; } }
    if (m3) { aall.x += v3.x; aall.y += v3.y; if (pk.w < 0) { aocp.x += v3.x; aocp.y += v3.y; } }
  }
  size_t o = (size_t)n * HD + lane * 2;
  _Float16 h0 = (_Float16)aall.x, h1 = (_Float16)aall.y;
  *(f16x2*)(xsah + o) = (f16x2){h0, h1};
  *(f16x2*)(xsal + o) = (f16x2){(_Float16)(aall.x - (float)h0), (_Float16)(aall.y - (float)h1)};
  _Float16 g0 = (_Float16)aocp.x, g1 = (_Float16)aocp.y;
  *(f16x2*)(xsoh + o) = (f16x2){g0, g1};
  *(f16x2*)(xsol + o) = (f16x2){(_Float16)(aocp.x - (float)g0), (_Float16)(aocp.y - (float)g1)};
}

// x (fp32) -> hi/lo fp16
__global__ __launch_bounds__(256) void split_x(const float* __restrict__ r,
    _Float16* __restrict__ rh, _Float16* __restrict__ rl) {
  int t = blockIdx.x * 256 + threadIdx.x;
  if (t >= NN * HD / 8) return;
  const float4* p = (const float4*)(r + (size_t)t * 8);
  float4 v0 = p[0], v1 = p[1];
  float vv[8] = {v0.x, v0.y, v0.z, v0.w, v1.x, v1.y, v1.z, v1.w};
  f16x8 hv, lv;
#pragma unroll
  for (int j = 0; j < 8; ++j) {
    _Float16 hh = (_Float16)vv[j];
    hv[j] = hh;
    lv[j] = (_Float16)(vv[j] - (float)hh);
  }
  *(f16x8*)(rh + (size_t)t * 8) = hv;
  *(f16x8*)(rl + (size_t)t * 8) = lv;
}

// pack [Wself; Wnbr] (256x128) into MFMA chunk order, hi/lo fp16.
__global__ void pack_w2(const float* __restrict__ Wself, const float* __restrict__ Wnbr,
    _Float16* __restrict__ oh, _Float16* __restrict__ ol) {
  int chunk = blockIdx.x;      // 64 chunks
  int lane = threadIdx.x;      // 64
  int ns = chunk & 7, kt = chunk >> 3;
  int n = ns * 16 + (lane & 15);
  int k0 = kt * 32 + (lane >> 4) * 8;
  f16x8 hv, lv;
#pragma unroll
  for (int j = 0; j < 8; ++j) {
    int k = k0 + j;
    float v = (k < 128) ? Wself[(size_t)k * 128 + n] : Wnbr[(size_t)(k - 128) * 128 + n];
    _Float16 hh = (_Float16)v;
    hv[j] = hh;
    lv[j] = (_Float16)(v - (float)hh);
  }
  *(f16x8*)(oh + (size_t)chunk * 512 + lane * 8) = hv;
  *(f16x8*)(ol + (size_t)chunk * 512 + lane * 8) = lv;
}

// pack W (KxN fp32 row-major) into MFMA-fragment order, hi/lo fp16.
__global__ void pack_w(const float* __restrict__ W, int K, int N,
    _Float16* __restrict__ oh, _Float16* __restrict__ ol) {
  int chunk = blockIdx.x;
  int lane = threadIdx.x;  // 64
  int NS = N >> 4;
  int ns = chunk % NS, kt = chunk / NS;
  int n = ns * 16 + (lane & 15);
  int k0 = kt * 32 + (lane >> 4) * 8;
  f16x8 hv, lv;
#pragma unroll
  for (int j = 0; j < 8; ++j) {
    float v = W[(size_t)(k0 + j) * N + n];
    _Float16 hh = (_Float16)v;
    hv[j] = hh;
    lv[j] = (_Float16)(v - (float)hh);
  }
  *(f16x8*)(oh + (size_t)chunk * 512 + lane * 8) = hv;
  *(f16x8*)(ol + (size_t)chunk * 512 + lane * 8) = lv;
}

// W34 = Wr3 @ Wp1 ; b34 = br3 @ Wp1 + bp1
__global__ void w34_kernel(const float* __restrict__ Wr3, const float* __restrict__ Wp1,
    const float* __restrict__ br3, const float* __restrict__ bp1,
    float* __restrict__ W34, float* __restrict__ b34) {
  int i = blockIdx.x, j = threadIdx.x;  // grid 256 x block 128
  float s = 0.f;
  for (int k = 0; k < 128; ++k) s += Wr3[i * 128 + k] * Wp1[k * 128 + j];
  W34[i * 128 + j] = s;
  if (i == 0) {
    float t = bp1[j];
    for (int k = 0; k < 128; ++k) t += br3[k] * Wp1[k * 128 + j];
    b34[j] = t;
  }
}

// ---------------- 2-buffer counted-vmcnt split-fp16 MFMA GEMM, 64x64 tile ----------------
// 256 threads = 4 waves (2x2 of 32x32). LDS: 2 buffers x 16KB {A: 4 msubs h 4KB + l 4KB;
// B: 4 nsubs h 4KB + l 4KB} = 32KB -> 5 blocks/CU (20 waves, ~62% occupancy; TLP hides
// latency instead of per-wave depth). Per iter: STAGE(kt+1, buf^1) -> vmcnt(4) ->
// s_barrier -> COMPUTE(kt) -> s_barrier. 4 dma per wave per stage.
// 1-D grid + bijective XCD-grouping swizzle (verified r9-r12).
template <int KT, int NS_B, int AMODE, int KT_NEXT, int NB>
__global__ __launch_bounds__(256) void gemm_ab(
    const _Float16* __restrict__ Ah, const _Float16* __restrict__ Al,
    const int* __restrict__ idx0, const int* __restrict__ idx1,
    const _Float16* __restrict__ Bh, const _Float16* __restrict__ Bl,
    const float* __restrict__ bias,
    _Float16* __restrict__ Oh, _Float16* __restrict__ Ol) {
  __shared__ char smem[32768] __attribute__((aligned(16)));
  float* sC = (float*)smem;                      // epilogue reuse: 64 x 68 (17.4KB)

  const int tid = threadIdx.x;
  const int w = tid >> 6, lane = tid & 63;
  const int l16 = lane & 15, g16 = lane >> 4;
  // XCD-grouping swizzle (row-panels multiple of 8): p = 8q + r
  const int f = blockIdx.x;
  const int r8 = f & 7;
  const int nb = (f >> 3) % NB;
  const int q8 = f / (8 * NB);
  const int bm = (q8 * 8 + r8) * 64, bn = nb * 64;
  const int w2r = w >> 1, w2c = w & 1;           // row-half / col-half (32x32 each)
  const int bmT = bm >> 4, bnS = bn >> 4;

  f32x4 acc[2][2];
#pragma unroll
  for (int i = 0; i < 2; ++i)
#pragma unroll
    for (int j = 0; j < 2; ++j) acc[i][j] = (f32x4)0.f;

  int i0w = 0, i1w = 0;
  if constexpr (AMODE == 1) {
    int rr = bm + w * 16 + l16;                  // wave stages msub w (16 rows)
    i0w = idx0[rr];
    i1w = idx1[rr];
  }

  auto STAGE = [&](int kt, int buf) {            // 4 dma16 per wave, uniformly
    char* base = smem + buf * 16384;
    if constexpr (AMODE == 0) {
      size_t ch = (size_t)(bmT + w) * KT + kt;   // A msub w, arrays h+l
      dma16((const char*)Ah + ch * 1024 + lane * 16, base + w * 1024);
      dma16((const char*)Al + ch * 1024 + lane * 16, base + 4096 + w * 1024);
    } else {
      int col = (kt & 3) * 32 + g16 * 8;
      int r = (kt < 4) ? i0w : i1w;
      dma16(Ah + (size_t)r * HD + col, base + w * 1024);
      dma16(Al + (size_t)r * HD + col, base + 4096 + w * 1024);
    }
    size_t chb = (size_t)kt * NS_B + bnS + w;    // B nsub w, arrays h+l
    dma16((const char*)Bh + chb * 1024 + lane * 16, base + 8192 + w * 1024);
    dma16((const char*)Bl + chb * 1024 + lane * 16, base + 12288 + w * 1024);
  };

  auto COMPUTE = [&](int buf) {
    const _Float16* sAh = (const _Float16*)(smem + buf * 16384);
    const _Float16* sAl = (const _Float16*)(smem + buf * 16384 + 4096);
    const _Float16* sBh = (const _Float16*)(smem + buf * 16384 + 8192);
    const _Float16* sBl = (const _Float16*)(smem + buf * 16384 + 12288);
    f16x8 ah[2], al[2];
#pragma unroll
    for (int mi = 0; mi < 2; ++mi) {
      ah[mi] = *(const f16x8*)(sAh + (w2r * 2 + mi) * 512 + lane * 8);
      al[mi] = *(const f16x8*)(sAl + (w2r * 2 + mi) * 512 + lane * 8);
    }
#pragma unroll
    for (int ni = 0; ni < 2; ++ni) {
      f16x8 bh = *(const f16x8*)(sBh + (w2c * 2 + ni) * 512 + lane * 8);
      f16x8 bl = *(const f16x8*)(sBl + (w2c * 2 + ni) * 512 + lane * 8);
#pragma unroll
      for (int mi = 0; mi < 2; ++mi) {
        acc[mi][ni] = __builtin_amdgcn_mfma_f32_16x16x32_f16(ah[mi], bh, acc[mi][ni], 0, 0, 0);
        acc[mi][ni] = __builtin_amdgcn_mfma_f32_16x16x32_f16(al[mi], bh, acc[mi][ni], 0, 0, 0);
        acc[mi][ni] = __builtin_amdgcn_mfma_f32_16x16x32_f16(ah[mi], bl, acc[mi][ni], 0, 0, 0);
      }
    }
  };

  // prologue: one stage in flight
  STAGE(0, 0);
#pragma unroll
  for (int kt = 0; kt < KT; ++kt) {
    if (kt + 1 < KT) {
      STAGE(kt + 1, (kt + 1) & 1);
      WAITVM4();
    } else {
      WAITVM0();
    }
    __builtin_amdgcn_s_barrier();
    COMPUTE(kt & 1);
    __builtin_amdgcn_s_barrier();
  }

  // epilogue: elu+bias -> sC (4 waves disjoint quadrants) -> repack to hi/lo chunks
#pragma unroll
  for (int ni = 0; ni < 2; ++ni) {
    int colL = (w2c * 2 + ni) * 16 + l16;
    float bv = bias[bn + colL];
#pragma unroll
    for (int mi = 0; mi < 2; ++mi) {
      int rowb = w2r * 32 + mi * 16 + g16 * 4;
#pragma unroll
      for (int r = 0; r < 4; ++r)
        sC[(rowb + r) * 68 + colL] = elu_f(acc[mi][ni][r] + bv);
    }
  }
  __syncthreads();
  const int bnT32 = bn >> 5;
#pragma unroll
  for (int s = 0; s < 2; ++s) {
    int chunkid = w * 2 + s;             // 8 chunks: 4 msubs x 2 ktl (64 cols)
    int msub = chunkid >> 1, ktl = chunkid & 1;
    int m = msub * 16 + l16;
    int cb = ktl * 32 + g16 * 8;
    f16x8 hv, lv;
#pragma unroll
    for (int j = 0; j < 8; ++j) {
      float v = sC[m * 68 + cb + j];
      _Float16 hh = (_Float16)v;
      hv[j] = hh;
      lv[j] = (_Float16)(v - (float)hh);
    }
    size_t gchunk = (size_t)(bmT + msub) * KT_NEXT + (bnT32 + ktl);
    *(f16x8*)((char*)Oh + gchunk * 1024 + lane * 16) = hv;
    *(f16x8*)((char*)Ol + gchunk * 1024 + lane * 16) = lv;
  }
}

// GNN reps, register-direct: 1 wave per 32x64 tile, grid (1564, 2). (verified r10-r12)
__global__ __launch_bounds__(64) void reps_direct(
    const _Float16* __restrict__ xh, const _Float16* __restrict__ xl,
    const _Float16* __restrict__ xsah, const _Float16* __restrict__ xsal,
    const _Float16* __restrict__ xsoh, const _Float16* __restrict__ xsol,
    const _Float16* __restrict__ Wsh, const _Float16* __restrict__ Wsl,
    const float* __restrict__ bias,
    _Float16* __restrict__ Oh, _Float16* __restrict__ Ol) {
  __shared__ float sC[32][68];
  const int lane = threadIdx.x;
  const int mt = blockIdx.x, nt = blockIdx.y;
  const int bm = mt * 32, bn = nt * 64;
  const int l16 = lane & 15, g16 = lane >> 4;

  f32x4 acc1[2][4], acc2[2][4];
#pragma unroll
  for (int i = 0; i < 2; ++i)
#pragma unroll
    for (int j = 0; j < 4; ++j) acc1[i][j] = (f32x4)0.f;

  auto CP3 = [&](f32x4 (*acc)[4], const f16x8* ah, const f16x8* al,
                 const f16x8* bh, const f16x8* bl) {
#pragma unroll
    for (int ni = 0; ni < 4; ++ni)
#pragma unroll
      for (int mi = 0; mi < 2; ++mi) {
        acc[mi][ni] = __builtin_amdgcn_mfma_f32_16x16x32_f16(ah[mi], bh[ni], acc[mi][ni], 0, 0, 0);
        acc[mi][ni] = __builtin_amdgcn_mfma_f32_16x16x32_f16(al[mi], bh[ni], acc[mi][ni], 0, 0, 0);
        acc[mi][ni] = __builtin_amdgcn_mfma_f32_16x16x32_f16(ah[mi], bl[ni], acc[mi][ni], 0, 0, 0);
      }
  };

#pragma unroll
  for (int kt = 0; kt < 4; ++kt) {
    f16x8 ah[2], al[2], bh[4], bl[4];
#pragma unroll
    for (int mi = 0; mi < 2; ++mi) {
      size_t off = (size_t)(bm + mi * 16 + l16) * HD + kt * 32 + g16 * 8;
      ah[mi] = *(const f16x8*)(xh + off);
      al[mi] = *(const f16x8*)(xl + off);
    }
#pragma unroll
    for (int ni = 0; ni < 4; ++ni) {
      size_t ch = (size_t)kt * 8 + nt * 4 + ni;
      bh[ni] = *(const f16x8*)(Wsh + ch * 512 + lane * 8);
      bl[ni] = *(const f16x8*)(Wsl + ch * 512 + lane * 8);
    }
    CP3(acc1, ah, al, bh, bl);
  }
#pragma unroll
  for (int i = 0; i < 2; ++i)
#pragma unroll
    for (int j = 0; j < 4; ++j) acc2[i][j] = acc1[i][j];

#pragma unroll
  for (int kt = 0; kt < 4; ++kt) {
    f16x8 aah[2], aal[2], aoh[2], aol[2], bh[4], bl[4];
#pragma unroll
    for (int mi = 0; mi < 2; ++mi) {
      size_t off = (size_t)(bm + mi * 16 + l16) * HD + kt * 32 + g16 * 8;
      aah[mi] = *(const f16x8*)(xsah + off);
      aal[mi] = *(const f16x8*)(xsal + off);
      aoh[mi] = *(const f16x8*)(xsoh + off);
      aol[mi] = *(const f16x8*)(xsol + off);
    }
#pragma unroll
    for (int ni = 0; ni < 4; ++ni) {
      size_t ch = (size_t)(kt + 4) * 8 + nt * 4 + ni;
      bh[ni] = *(const f16x8*)(Wsh + ch * 512 + lane * 8);
      bl[ni] = *(const f16x8*)(Wsl + ch * 512 + lane * 8);
    }
    CP3(acc1, aah, aal, bh, bl);
    CP3(acc2, aoh, aol, bh, bl);
  }

#pragma unroll
  for (int ni = 0; ni < 4; ++ni) {
    int colL = ni * 16 + l16;
    float bv = bias[bn + colL];
#pragma unroll
    for (int mi = 0; mi < 2; ++mi) {
      int rowb = mi * 16 + g16 * 4;
#pragma unroll
      for (int r = 0; r < 4; ++r)
        sC[rowb + r][colL] = elu_f(acc1[mi][ni][r] + bv) - elu_f(acc2[mi][ni][r] + bv);
    }
  }
  __syncthreads();
#pragma unroll
  for (int c = 0; c < 4; ++c) {
    int msub = c >> 1, ktl = c & 1;
    int m = msub * 16 + l16;
    int cb = ktl * 32 + g16 * 8;
    int grow = bm + m;
    if (grow < NN) {
      f16x8 hv, lv;
#pragma unroll
      for (int j = 0; j < 8; ++j) {
        float v = sC[m][cb + j];
        _Float16 hh = (_Float16)v;
        hv[j] = hh;
        lv[j] = (_Float16)(v - (float)hh);
      }
      *(f16x8*)(Oh + (size_t)grow * HD + bn + cb) = hv;
      *(f16x8*)(Ol + (size_t)grow * HD + bn + cb) = lv;
    }
  }
}

// fused layer3+sel, 3-buffer counted-vmcnt: 4 waves, 64-row block. (verified r8-r12)
__global__ __launch_bounds__(256) void gemm3_sel(
    const _Float16* __restrict__ Ah, const _Float16* __restrict__ Al,
    const _Float16* __restrict__ Bh, const _Float16* __restrict__ Bl,
    const float* __restrict__ b34,
    const int* __restrict__ ei, const int* __restrict__ batchv, const int* __restrict__ yv,
    const float* __restrict__ Wp2, const float* __restrict__ bp2,
    float* __restrict__ sel, int* __restrict__ seg, int co) {
  __shared__ char smem[73728] __attribute__((aligned(16)));
  const int tid = threadIdx.x;
  const int w = tid >> 6, lane = tid & 63;
  const int l16 = lane & 15, g16 = lane >> 4;
  const int mt = blockIdx.x;

  f32x4 acc[8];
#pragma unroll
  for (int j = 0; j < 8; ++j) acc[j] = (f32x4)0.f;

  auto STAGE = [&](int kt, int buf) {
    char* base = smem + buf * 24576;
    size_t ch = (size_t)(mt * 4 + w) * 8 + kt;
    dma16((const char*)Ah + ch * 1024 + lane * 16, base + w * 1024);
    dma16((const char*)Al + ch * 1024 + lane * 16, base + 4096 + w * 1024);
#pragma unroll
    for (int s = 0; s < 2; ++s) {
      int nsub = w * 2 + s;
      size_t chb = (size_t)kt * 8 + nsub;
      dma16((const char*)Bh + chb * 1024 + lane * 16, base + 8192 + nsub * 1024);
      dma16((const char*)Bl + chb * 1024 + lane * 16, base + 16384 + nsub * 1024);
    }
  };

  auto COMPUTE = [&](int buf) {
    const _Float16* sAh = (const _Float16*)(smem + buf * 24576);
    const _Float16* sAl = (const _Float16*)(smem + buf * 24576 + 4096);
    const _Float16* sBh = (const _Float16*)(smem + buf * 24576 + 8192);
    const _Float16* sBl = (const _Float16*)(smem + buf * 24576 + 16384);
    f16x8 ah = *(const f16x8*)(sAh + w * 512 + lane * 8);
    f16x8 al = *(const f16x8*)(sAl + w * 512 + lane * 8);
#pragma unroll
    for (int ni = 0; ni < 8; ++ni) {
      f16x8 bh = *(const f16x8*)(sBh + ni * 512 + lane * 8);
      f16x8 bl = *(const f16x8*)(sBl + ni * 512 + lane * 8);
      acc[ni] = __builtin_amdgcn_mfma_f32_16x16x32_f16(ah, bh, acc[ni], 0, 0, 0);
      acc[ni] = __builtin_amdgcn_mfma_f32_16x16x32_f16(al, bh, acc[ni], 0, 0, 0);
      acc[ni] = __builtin_amdgcn_mfma_f32_16x16x32_f16(ah, bl, acc[ni], 0, 0, 0);
    }
  };

  STAGE(0, 0);
  STAGE(1, 1);
#pragma unroll
  for (int kt = 0; kt < 8; ++kt) {
    if (kt + 2 < 8) STAGE(kt + 2, (kt + 2) % 3);
    if (kt < 6) WAITVM12();
    else if (kt == 6) WAITVM6();
    else WAITVM0();
    __builtin_amdgcn_s_barrier();
    COMPUTE(kt % 3);
    __builtin_amdgcn_s_barrier();
  }

  float bb[8];
#pragma unroll
  for (int ni = 0; ni < 8; ++ni) bb[ni] = b34[ni * 16 + l16];

#pragma unroll
  for (int rr = 0; rr < 4; ++rr) {
    int row = w * 16 + g16 * 4 + rr;
    int e = co + mt * 64 + row;
    int s = ei[NOCP + e];
    int gg = batchv[s];
    int c = yv[gg];
    float a = 0.f;
#pragma unroll
    for (int ni = 0; ni < 8; ++ni)
      a += elu_f(acc[ni][rr] + bb[ni]) * Wp2[(ni * 16 + l16) * 10 + c];
    a += __shfl_xor(a, 1);
    a += __shfl_xor(a, 2);
    a += __shfl_xor(a, 4);
    a += __shfl_xor(a, 8);
    if (l16 == 0) { sel[e] = a + bp2[c]; seg[e] = gg; }
  }
}

// ---------------- tail: segment softmax/argmax ----------------
__global__ __launch_bounds__(256) void segmax_sel(const float* __restrict__ sel,
    const int* __restrict__ seg, unsigned* __restrict__ mx_enc) {
  __shared__ unsigned sm[NG];
  int tid = threadIdx.x;
  if (tid < NG) sm[tid] = 0u;
  __syncthreads();
  for (int i = blockIdx.x * blockDim.x + tid; i < EAVA; i += gridDim.x * blockDim.x)
    atomicMax(&sm[seg[i]], fenc(sel[i]));
  __syncthreads();
  if (tid < NG) atomicMax(&mx_enc[tid], sm[tid]);
}

__global__ __launch_bounds__(256) void exden_kernel(const float* __restrict__ sel,
    const int* __restrict__ seg, const unsigned* __restrict__ mx_enc,
    float* __restrict__ denom, float* __restrict__ out_probs) {
  __shared__ float sd[NG];
  __shared__ float smx[NG];
  int tid = threadIdx.x;
  if (tid < NG) { smx[tid] = fdec(mx_enc[tid]); sd[tid] = 0.f; }
  __syncthreads();
  for (int i = blockIdx.x * blockDim.x + tid; i < EAVA; i += gridDim.x * blockDim.x) {
    int g = seg[i];
    float ex = expf(sel[i] - smx[g]);
    out_probs[i] = ex;
    atomicAdd(&sd[g], ex);
  }
  __syncthreads();
  if (tid < NG) atomicAdd(&denom[tid], sd[tid]);
}

__global__ __launch_bounds__(256) void probpmax_kernel(const int* __restrict__ seg,
    const float* __restrict__ denom, float* __restrict__ out_probs,
    unsigned* __restrict__ pmax_enc) {
  __shared__ float sden[NG];
  __shared__ unsigned sp[NG];
  int tid = threadIdx.x;
  if (tid < NG) { sden[tid] = denom[tid]; sp[tid] = 0u; }
  __syncthreads();
  for (int i = blockIdx.x * blockDim.x + tid; i < EAVA; i += gridDim.x * blockDim.x) {
    int g = seg[i];
    float p = out_probs[i] / sden[g];
    out_probs[i] = p;
    atomicMax(&sp[g], fenc(p));
  }
  __syncthreads();
  if (tid < NG) atomicMax(&pmax_enc[tid], sp[tid]);
}

__global__ __launch_bounds__(256) void argmin_kernel(const int* __restrict__ seg,
    const float* __restrict__ out_probs, const unsigned* __restrict__ pmax_enc,
    int* __restrict__ amin) {
  __shared__ float spm[NG];
  __shared__ int sa[NG];
  int tid = threadIdx.x;
  if (tid < NG) { spm[tid] = fdec(pmax_enc[tid]); sa[tid] = EAVA; }
  __syncthreads();
  for (int i = blockIdx.x * blockDim.x + tid; i < EAVA; i += gridDim.x * blockDim.x) {
    int g = seg[i];
    if (out_probs[i] == spm[g]) atomicMin(&sa[g], i);
  }
  __syncthreads();
  if (tid < NG) atomicMin(&amin[tid], sa[tid]);
}

__global__ void finalize_kernel(const unsigned* __restrict__ pmax_enc,
    const int* __restrict__ amin, float* __restrict__ out) {
  int g = threadIdx.x;
  if (g < NG) {
    out[EAVA + g] = fdec(pmax_enc[g]);
    out[EAVA + NG + g] = (float)amin[g];
  }
}

extern "C" void kernel_launch(void* const* d_in, const int* in_sizes, int n_in,
                              void* d_out, int out_size, void* d_ws, size_t ws_size,
                              hipStream_t stream) {
  const float* x      = (const float*)d_in[0];
  const int*   ei     = (const int*)d_in[1];
  const int*   batchv = (const int*)d_in[2];
  const int*   yv     = (const int*)d_in[3];
  const float* Wself = (const float*)d_in[5];
  const float* Wnbr  = (const float*)d_in[6];
  const float* bgnn  = (const float*)d_in[7];
  const float* Wr1   = (const float*)d_in[8];
  const float* br1   = (const float*)d_in[9];
  const float* Wr2   = (const float*)d_in[10];
  const float* br2   = (const float*)d_in[11];
  const float* Wr3   = (const float*)d_in[12];
  const float* br3   = (const float*)d_in[13];
  const float* Wp1   = (const float*)d_in[14];
  const float* bp1   = (const float*)d_in[15];
  const float* Wp2   = (const float*)d_in[16];
  const float* bp2   = (const float*)d_in[17];
  float* out = (float*)d_out;

  char* wp = (char*)d_ws;
  auto alloc = [&](size_t bytes) -> char* {
    char* p = wp;
    wp += (bytes + 255) & ~(size_t)255;
    return p;
  };
  // 6 contiguous split arrays (padded to NNP rows): xh, xl, xsah, xsal, xsoh, xsol
  _Float16* xsplit = (_Float16*)alloc((size_t)6 * NNP * HD * 2);
  _Float16* xh   = xsplit + (size_t)0 * NNP * HD;
  _Float16* xl   = xsplit + (size_t)1 * NNP * HD;
  _Float16* xsah = xsplit + (size_t)2 * NNP * HD;
  _Float16* xsal = xsplit + (size_t)3 * NNP * HD;
  _Float16* xsoh = xsplit + (size_t)4 * NNP * HD;
  _Float16* xsol = xsplit + (size_t)5 * NNP * HD;
  _Float16*  reps_h   = (_Float16*)alloc((size_t)NN * HD * 2);
  _Float16*  reps_l   = (_Float16*)alloc((size_t)NN * HD * 2);
  int*       cnt      = (int*)alloc((size_t)NN * 4);
  int*       bucket   = (int*)alloc((size_t)NN * CAP * 4);
  float*     sel      = (float*)alloc((size_t)EAVA * 4);
  int*       seg      = (int*)alloc((size_t)EAVA * 4);
  unsigned*  mx_enc   = (unsigned*)alloc(NG * 4);
  float*     denom    = (float*)alloc(NG * 4);
  unsigned*  pmax_enc = (unsigned*)alloc(NG * 4);
  int*       amin     = (int*)alloc(NG * 4);
  // packed weights (hi/lo)
  _Float16*  Wsh  = (_Float16*)alloc((size_t)64 * 1024);   // [Wself;Wnbr] 8kt x 8ns
  _Float16*  Wsl  = (_Float16*)alloc((size_t)64 * 1024);
  _Float16*  Wr1h = (_Float16*)alloc((size_t)8 * 32 * 1024);
  _Float16*  Wr1l = (_Float16*)alloc((size_t)8 * 32 * 1024);
  _Float16*  Wr2h = (_Float16*)alloc((size_t)16 * 16 * 1024);
  _Float16*  Wr2l = (_Float16*)alloc((size_t)16 * 16 * 1024);
  float*     W34  = (float*)alloc((size_t)256 * 128 * 4);
  float*     b34  = (float*)alloc(128 * 4);
  _Float16*  W34h = (_Float16*)alloc((size_t)8 * 8 * 1024);
  _Float16*  W34l = (_Float16*)alloc((size_t)8 * 8 * 1024);
  // per-chunk activation pack buffers
  _Float16*  b1h = (_Float16*)alloc((size_t)(CHNK / 16) * 16 * 1024);
  _Float16*  b1l = (_Float16*)alloc((size_t)(CHNK / 16) * 16 * 1024);
  _Float16*  b2h = (_Float16*)alloc((size_t)(CHNK / 16) * 8 * 1024);
  _Float16*  b2l = (_Float16*)alloc((size_t)(CHNK / 16) * 8 * 1024);
  (void)ws_size;

  // ---- prep ----
  zero_i<<<64, 256, 0, stream>>>(cnt, NN);
  init_small<<<1, 64, 0, stream>>>(mx_enc, denom, pmax_enc, amin);
  zero_tails<<<18, 256, 0, stream>>>(xsplit);
  bucket_kernel<<<NE / 256, 256, 0, stream>>>(ei, cnt, bucket);
  gather_kernel<<<(NN + 3) / 4, 256, 0, stream>>>(x, cnt, bucket, xsah, xsal, xsoh, xsol);
  split_x<<<(NN * HD / 8 + 255) / 256, 256, 0, stream>>>(x, xh, xl);
  pack_w2<<<64, 64, 0, stream>>>(Wself, Wnbr, Wsh, Wsl);
  reps_direct<<<dim3(NNP / 32, 2), 64, 0, stream>>>(xh, xl, xsah, xsal, xsoh, xsol, Wsh, Wsl,
                                                    bgnn, reps_h, reps_l);
  w34_kernel<<<256, 128, 0, stream>>>(Wr3, Wp1, br3, bp1, W34, b34);
  pack_w<<<8 * 32, 64, 0, stream>>>(Wr1, 256, 512, Wr1h, Wr1l);
  pack_w<<<16 * 16, 64, 0, stream>>>(Wr2, 512, 256, Wr2h, Wr2l);
  pack_w<<<8 * 8, 64, 0, stream>>>(W34, 256, 128, W34h, W34l);

  // ---- per-edge MLP: 7 chunks of 32768 ----
  for (int c = 0; c < 7; ++c) {
    int co = c * CHNK;
    gemm_ab<8, 32, 1, 16, 8><<<(CHNK / 64) * 8, 256, 0, stream>>>(
        reps_h, reps_l, ei + NOCP + co, ei + NE + NOCP + co, Wr1h, Wr1l, br1, b1h, b1l);
    gemm_ab<16, 16, 0, 8, 4><<<(CHNK / 64) * 4, 256, 0, stream>>>(
        b1h, b1l, nullptr, nullptr, Wr2h, Wr2l, br2, b2h, b2l);
    gemm3_sel<<<CHNK / 64, 256, 0, stream>>>(
        b2h, b2l, W34h, W34l, b34, ei, batchv, yv, Wp2, bp2, sel, seg, co);
  }

  // ---- segment softmax + argmax ----
  segmax_sel<<<112, 256, 0, stream>>>(sel, seg, mx_enc);
  exden_kernel<<<112, 256, 0, stream>>>(sel, seg, mx_enc, denom, out);
  probpmax_kernel<<<112, 256, 0, stream>>>(seg, denom, out, pmax_enc);
  argmin_kernel<<<112, 256, 0, stream>>>(seg, out, pmax_enc, amin);
  finalize_kernel<<<1, 64, 0, stream>>>(pmax_enc, amin, out);
}

// Round 14
// 802.312 us; speedup vs baseline: 1.1612x; 1.1612x over previous
//
#include <hip/hip_runtime.h>

#define NN   50000
#define NNP  50048            // 1564 * 32 (padded M for reps tiles)
#define NE   262144
#define NOCP 32768
#define EAVA (NE - NOCP)      // 229376 = 7 * 32768
#define NG   64
#define HD   128
#define CAP  48
#define CHNK 32768

typedef _Float16 f16x8 __attribute__((ext_vector_type(8)));
typedef _Float16 f16x2 __attribute__((ext_vector_type(2)));
typedef float f32x4 __attribute__((ext_vector_type(4)));

// counted vmcnt waits
#define WAITVM12() asm volatile("s_waitcnt vmcnt(12)" ::: "memory")
#define WAITVM6()  asm volatile("s_waitcnt vmcnt(6)" ::: "memory")
#define WAITVM4()  asm volatile("s_waitcnt vmcnt(4)" ::: "memory")
#define WAITVM0()  asm volatile("s_waitcnt vmcnt(0)" ::: "memory")

__device__ __forceinline__ float elu_f(float v) { return v > 0.f ? v : (expf(v) - 1.f); }

__device__ __forceinline__ unsigned fenc(float f) {
  unsigned u = __float_as_uint(f);
  return (u & 0x80000000u) ? ~u : (u | 0x80000000u);
}
__device__ __forceinline__ float fdec(unsigned u) {
  return __uint_as_float((u & 0x80000000u) ? (u & 0x7fffffffu) : ~u);
}

// async global->LDS 16B per lane; LDS dst = base + lane*16 (wave-uniform base)
__device__ __forceinline__ void dma16(const void* g, void* l) {
  __builtin_amdgcn_global_load_lds((const __attribute__((address_space(1))) unsigned int*)g,
                                   (__attribute__((address_space(3))) unsigned int*)l,
                                   16, 0, 0);
}

__global__ __launch_bounds__(256) void zero_i(int* __restrict__ p, int n) {
  for (int i = blockIdx.x * 256 + threadIdx.x; i < n; i += gridDim.x * 256) p[i] = 0;
}

__global__ void init_small(unsigned* mx_enc, float* denom, unsigned* pmax_enc, int* amin) {
  int t = threadIdx.x;
  if (t < NG) { mx_enc[t] = 0u; denom[t] = 0.f; pmax_enc[t] = 0u; amin[t] = EAVA; }
}

// zero padding rows NN..NNP-1 of the 6 split arrays (one contiguous block)
__global__ __launch_bounds__(256) void zero_tails(_Float16* __restrict__ base) {
  int t = blockIdx.x * 256 + threadIdx.x;           // 6 arrays * 768 f16x8
  if (t >= 6 * 768) return;
  int arr = t / 768, off = t % 768;
  f16x8 z = {};
  *(f16x8*)(base + (size_t)arr * NNP * HD + (size_t)NN * HD + (size_t)off * 8) = z;
}

// ---------------- GNN aggregation (bucket-then-gather) ----------------
__global__ __launch_bounds__(256) void bucket_kernel(const int* __restrict__ ei,
    int* __restrict__ cnt, int* __restrict__ bucket) {
  int e = blockIdx.x * 256 + threadIdx.x;
  if (e >= NE) return;
  int dst = ei[NE + e];
  int src = ei[e];
  int slot = atomicAdd(&cnt[dst], 1);
  if (slot < CAP)
    bucket[(size_t)dst * CAP + slot] = (int)((unsigned)src | (e < NOCP ? 0x80000000u : 0u));
}

// gather: 4-wide unrolled, fp32 accumulate, emit split hi/lo fp16 (verified rounds 5-13)
__global__ __launch_bounds__(256) void gather_kernel(const float* __restrict__ x,
    const int* __restrict__ cnt, const int* __restrict__ bucket,
    _Float16* __restrict__ xsah, _Float16* __restrict__ xsal,
    _Float16* __restrict__ xsoh, _Float16* __restrict__ xsol) {
  int n = blockIdx.x * 4 + (threadIdx.x >> 6);
  if (n >= NN) return;
  int lane = threadIdx.x & 63;
  int c = cnt[n];
  if (c > CAP) c = CAP;
  float2 aall = make_float2(0.f, 0.f), aocp = aall;
  const int* bk = bucket + (size_t)n * CAP;
  for (int i0 = 0; i0 < c; i0 += 4) {
    int4 pk = *(const int4*)(bk + i0);
    bool m1 = (i0 + 1 < c), m2 = (i0 + 2 < c), m3 = (i0 + 3 < c);
    int r0 = pk.x & 0x7fffffff;
    int r1 = m1 ? (pk.y & 0x7fffffff) : 0;
    int r2 = m2 ? (pk.z & 0x7fffffff) : 0;
    int r3 = m3 ? (pk.w & 0x7fffffff) : 0;
    float2 v0 = *(const float2*)(x + (size_t)r0 * HD + lane * 2);
    float2 v1 = *(const float2*)(x + (size_t)r1 * HD + lane * 2);
    float2 v2 = *(const float2*)(x + (size_t)r2 * HD + lane * 2);
    float2 v3 = *(const float2*)(x + (size_t)r3 * HD + lane * 2);
    aall.x += v0.x; aall.y += v0.y;
    if (pk.x < 0) { aocp.x += v0.x; aocp.y += v0.y; }
    if (m1) { aall.x += v1.x; aall.y += v1.y; if (pk.y < 0) { aocp.x += v1.x; aocp.y += v1.y; } }
    if (m2) { aall.x += v2.x; aall.y += v2.y; if (pk.z < 0) { aocp.x += v2.x; aocp.y += v2.y; } }
    if (m3) { aall.x += v3.x; aall.y += v3.y; if (pk.w < 0) { aocp.x += v3.x; aocp.y += v3.y; } }
  }
  size_t o = (size_t)n * HD + lane * 2;
  _Float16 h0 = (_Float16)aall.x, h1 = (_Float16)aall.y;
  *(f16x2*)(xsah + o) = (f16x2){h0, h1};
  *(f16x2*)(xsal + o) = (f16x2){(_Float16)(aall.x - (float)h0), (_Float16)(aall.y - (float)h1)};
  _Float16 g0 = (_Float16)aocp.x, g1 = (_Float16)aocp.y;
  *(f16x2*)(xsoh + o) = (f16x2){g0, g1};
  *(f16x2*)(xsol + o) = (f16x2){(_Float16)(aocp.x - (float)g0), (_Float16)(aocp.y - (float)g1)};
}

// x (fp32) -> hi/lo fp16
__global__ __launch_bounds__(256) void split_x(const float* __restrict__ r,
    _Float16* __restrict__ rh, _Float16* __restrict__ rl) {
  int t = blockIdx.x * 256 + threadIdx.x;
  if (t >= NN * HD / 8) return;
  const float4* p = (const float4*)(r + (size_t)t * 8);
  float4 v0 = p[0], v1 = p[1];
  float vv[8] = {v0.x, v0.y, v0.z, v0.w, v1.x, v1.y, v1.z, v1.w};
  f16x8 hv, lv;
#pragma unroll
  for (int j = 0; j < 8; ++j) {
    _Float16 hh = (_Float16)vv[j];
    hv[j] = hh;
    lv[j] = (_Float16)(vv[j] - (float)hh);
  }
  *(f16x8*)(rh + (size_t)t * 8) = hv;
  *(f16x8*)(rl + (size_t)t * 8) = lv;
}

// pack [Wself; Wnbr] (256x128) into MFMA chunk order, hi/lo fp16.
__global__ void pack_w2(const float* __restrict__ Wself, const float* __restrict__ Wnbr,
    _Float16* __restrict__ oh, _Float16* __restrict__ ol) {
  int chunk = blockIdx.x;      // 64 chunks
  int lane = threadIdx.x;      // 64
  int ns = chunk & 7, kt = chunk >> 3;
  int n = ns * 16 + (lane & 15);
  int k0 = kt * 32 + (lane >> 4) * 8;
  f16x8 hv, lv;
#pragma unroll
  for (int j = 0; j < 8; ++j) {
    int k = k0 + j;
    float v = (k < 128) ? Wself[(size_t)k * 128 + n] : Wnbr[(size_t)(k - 128) * 128 + n];
    _Float16 hh = (_Float16)v;
    hv[j] = hh;
    lv[j] = (_Float16)(v - (float)hh);
  }
  *(f16x8*)(oh + (size_t)chunk * 512 + lane * 8) = hv;
  *(f16x8*)(ol + (size_t)chunk * 512 + lane * 8) = lv;
}

// pack W (KxN fp32 row-major) into MFMA-fragment order, hi/lo fp16.
__global__ void pack_w(const float* __restrict__ W, int K, int N,
    _Float16* __restrict__ oh, _Float16* __restrict__ ol) {
  int chunk = blockIdx.x;
  int lane = threadIdx.x;  // 64
  int NS = N >> 4;
  int ns = chunk % NS, kt = chunk / NS;
  int n = ns * 16 + (lane & 15);
  int k0 = kt * 32 + (lane >> 4) * 8;
  f16x8 hv, lv;
#pragma unroll
  for (int j = 0; j < 8; ++j) {
    float v = W[(size_t)(k0 + j) * N + n];
    _Float16 hh = (_Float16)v;
    hv[j] = hh;
    lv[j] = (_Float16)(v - (float)hh);
  }
  *(f16x8*)(oh + (size_t)chunk * 512 + lane * 8) = hv;
  *(f16x8*)(ol + (size_t)chunk * 512 + lane * 8) = lv;
}

// W34 = Wr3 @ Wp1 ; b34 = br3 @ Wp1 + bp1
__global__ void w34_kernel(const float* __restrict__ Wr3, const float* __restrict__ Wp1,
    const float* __restrict__ br3, const float* __restrict__ bp1,
    float* __restrict__ W34, float* __restrict__ b34) {
  int i = blockIdx.x, j = threadIdx.x;  // grid 256 x block 128
  float s = 0.f;
  for (int k = 0; k < 128; ++k) s += Wr3[i * 128 + k] * Wp1[k * 128 + j];
  W34[i * 128 + j] = s;
  if (i == 0) {
    float t = bp1[j];
    for (int k = 0; k < 128; ++k) t += br3[k] * Wp1[k * 128 + j];
    b34[j] = t;
  }
}

// ---------------- layer-1 GEMM: interleaved-hl gathered A ----------------
// reps_hl layout: row = 512B = 4 kt-blocks of 128B = [h 64B | l 64B] (8 slots of 16B).
// One dma16 stages 8 rows x one full 128B line (slot XOR-swizzled on the GLOBAL side,
// LDS dest linear; fragment read applies the same XOR -> 2 lanes/bank, free).
// 64x64 tile, 4 waves (2x2 of 32x32), 2 buffers x 16KB, counted vmcnt(4) schedule,
// XCD-grouping swizzle. Epilogue identical to gemm_ab (b1 packed chunks).
template <int NB>
__global__ __launch_bounds__(256) void gemm1_il(
    const _Float16* __restrict__ Rhl,
    const int* __restrict__ idx0, const int* __restrict__ idx1,
    const _Float16* __restrict__ Bh, const _Float16* __restrict__ Bl,
    const float* __restrict__ bias,
    _Float16* __restrict__ Oh, _Float16* __restrict__ Ol) {
  __shared__ char smem[32768] __attribute__((aligned(16)));
  float* sC = (float*)smem;                      // epilogue reuse: 64 x 68

  const int tid = threadIdx.x;
  const int w = tid >> 6, lane = tid & 63;
  const int l16 = lane & 15, g16 = lane >> 4;
  const int f = blockIdx.x;
  const int r8 = f & 7;
  const int nb = (f >> 3) % NB;
  const int q8 = f / (8 * NB);
  const int bm = (q8 * 8 + r8) * 64, bn = nb * 64;
  const int w2r = w >> 1, w2c = w & 1;
  const int bmT = bm >> 4, bnS = bn >> 4;

  f32x4 acc[2][2];
#pragma unroll
  for (int i = 0; i < 2; ++i)
#pragma unroll
    for (int j = 0; j < 2; ++j) acc[i][j] = (f32x4)0.f;

  // per-lane gather rows: dma #s covers rows s*8..s*8+7 of msub w, lane>>3 = local row
  const int rl = lane >> 3, t8 = lane & 7;
  const int sub = t8 ^ (rl & 7);                 // swizzled 16B slot within 128B block
  const int i0a = idx0[bm + w * 16 + rl];
  const int i0b = idx0[bm + w * 16 + 8 + rl];
  const int i1a = idx1[bm + w * 16 + rl];
  const int i1b = idx1[bm + w * 16 + 8 + rl];

  auto STAGE = [&](int kt, int buf) {            // 4 dma16 per wave (2 A + 2 B)
    char* base = smem + buf * 16384;
    int ktb = kt & 3;
#pragma unroll
    for (int s = 0; s < 2; ++s) {
      int r = (kt < 4) ? (s == 0 ? i0a : i0b) : (s == 0 ? i1a : i1b);
      dma16(Rhl + (size_t)r * 256 + ktb * 64 + sub * 8,
            base + w * 2048 + s * 1024 + lane * 16);
    }
    size_t chb = (size_t)kt * 32 + bnS + w;      // B nsub w (unchanged packed chunks)
    dma16((const char*)Bh + chb * 1024 + lane * 16, base + 8192 + w * 1024);
    dma16((const char*)Bl + chb * 1024 + lane * 16, base + 12288 + w * 1024);
  };

  auto COMPUTE = [&](int buf) {
    const _Float16* sA = (const _Float16*)(smem + buf * 16384);      // 8KB interleaved
    const _Float16* sBh = (const _Float16*)(smem + buf * 16384 + 8192);
    const _Float16* sBl = (const _Float16*)(smem + buf * 16384 + 12288);
    const int sw = l16 & 7;
    f16x8 ah[2], al[2];
#pragma unroll
    for (int mi = 0; mi < 2; ++mi) {
      const _Float16* mb = sA + (w2r * 2 + mi) * 1024 + l16 * 64;
      ah[mi] = *(const f16x8*)(mb + (g16 ^ sw) * 8);
      al[mi] = *(const f16x8*)(mb + ((g16 + 4) ^ sw) * 8);
    }
#pragma unroll
    for (int ni = 0; ni < 2; ++ni) {
      f16x8 bh = *(const f16x8*)(sBh + (w2c * 2 + ni) * 512 + lane * 8);
      f16x8 bl = *(const f16x8*)(sBl + (w2c * 2 + ni) * 512 + lane * 8);
#pragma unroll
      for (int mi = 0; mi < 2; ++mi) {
        acc[mi][ni] = __builtin_amdgcn_mfma_f32_16x16x32_f16(ah[mi], bh, acc[mi][ni], 0, 0, 0);
        acc[mi][ni] = __builtin_amdgcn_mfma_f32_16x16x32_f16(al[mi], bh, acc[mi][ni], 0, 0, 0);
        acc[mi][ni] = __builtin_amdgcn_mfma_f32_16x16x32_f16(ah[mi], bl, acc[mi][ni], 0, 0, 0);
      }
    }
  };

  STAGE(0, 0);
#pragma unroll
  for (int kt = 0; kt < 8; ++kt) {
    if (kt + 1 < 8) {
      STAGE(kt + 1, (kt + 1) & 1);
      WAITVM4();
    } else {
      WAITVM0();
    }
    __builtin_amdgcn_s_barrier();
    COMPUTE(kt & 1);
    __builtin_amdgcn_s_barrier();
  }

  // epilogue: elu+bias -> sC -> repack to hi/lo packed chunks (KT_NEXT = 16)
#pragma unroll
  for (int ni = 0; ni < 2; ++ni) {
    int colL = (w2c * 2 + ni) * 16 + l16;
    float bv = bias[bn + colL];
#pragma unroll
    for (int mi = 0; mi < 2; ++mi) {
      int rowb = w2r * 32 + mi * 16 + g16 * 4;
#pragma unroll
      for (int r = 0; r < 4; ++r)
        sC[(rowb + r) * 68 + colL] = elu_f(acc[mi][ni][r] + bv);
    }
  }
  __syncthreads();
  const int bnT32 = bn >> 5;
#pragma unroll
  for (int s = 0; s < 2; ++s) {
    int chunkid = w * 2 + s;
    int msub = chunkid >> 1, ktl = chunkid & 1;
    int m = msub * 16 + l16;
    int cb = ktl * 32 + g16 * 8;
    f16x8 hv, lv;
#pragma unroll
    for (int j = 0; j < 8; ++j) {
      float v = sC[m * 68 + cb + j];
      _Float16 hh = (_Float16)v;
      hv[j] = hh;
      lv[j] = (_Float16)(v - (float)hh);
    }
    size_t gchunk = (size_t)(bmT + msub) * 16 + (bnT32 + ktl);
    *(f16x8*)((char*)Oh + gchunk * 1024 + lane * 16) = hv;
    *(f16x8*)((char*)Ol + gchunk * 1024 + lane * 16) = lv;
  }
}

// ---------------- 2-buffer counted-vmcnt split-fp16 MFMA GEMM, 64x64 tile ----------------
// (verified r13 schedule; AMODE 0 packed-chunk A only — used for layer 2)
template <int KT, int NS_B, int KT_NEXT, int NB>
__global__ __launch_bounds__(256) void gemm_ab(
    const _Float16* __restrict__ Ah, const _Float16* __restrict__ Al,
    const _Float16* __restrict__ Bh, const _Float16* __restrict__ Bl,
    const float* __restrict__ bias,
    _Float16* __restrict__ Oh, _Float16* __restrict__ Ol) {
  __shared__ char smem[32768] __attribute__((aligned(16)));
  float* sC = (float*)smem;                      // epilogue reuse: 64 x 68

  const int tid = threadIdx.x;
  const int w = tid >> 6, lane = tid & 63;
  const int l16 = lane & 15, g16 = lane >> 4;
  const int f = blockIdx.x;
  const int r8 = f & 7;
  const int nb = (f >> 3) % NB;
  const int q8 = f / (8 * NB);
  const int bm = (q8 * 8 + r8) * 64, bn = nb * 64;
  const int w2r = w >> 1, w2c = w & 1;
  const int bmT = bm >> 4, bnS = bn >> 4;

  f32x4 acc[2][2];
#pragma unroll
  for (int i = 0; i < 2; ++i)
#pragma unroll
    for (int j = 0; j < 2; ++j) acc[i][j] = (f32x4)0.f;

  auto STAGE = [&](int kt, int buf) {            // 4 dma16 per wave
    char* base = smem + buf * 16384;
    size_t ch = (size_t)(bmT + w) * KT + kt;     // A msub w
    dma16((const char*)Ah + ch * 1024 + lane * 16, base + w * 1024);
    dma16((const char*)Al + ch * 1024 + lane * 16, base + 4096 + w * 1024);
    size_t chb = (size_t)kt * NS_B + bnS + w;    // B nsub w
    dma16((const char*)Bh + chb * 1024 + lane * 16, base + 8192 + w * 1024);
    dma16((const char*)Bl + chb * 1024 + lane * 16, base + 12288 + w * 1024);
  };

  auto COMPUTE = [&](int buf) {
    const _Float16* sAh = (const _Float16*)(smem + buf * 16384);
    const _Float16* sAl = (const _Float16*)(smem + buf * 16384 + 4096);
    const _Float16* sBh = (const _Float16*)(smem + buf * 16384 + 8192);
    const _Float16* sBl = (const _Float16*)(smem + buf * 16384 + 12288);
    f16x8 ah[2], al[2];
#pragma unroll
    for (int mi = 0; mi < 2; ++mi) {
      ah[mi] = *(const f16x8*)(sAh + (w2r * 2 + mi) * 512 + lane * 8);
      al[mi] = *(const f16x8*)(sAl + (w2r * 2 + mi) * 512 + lane * 8);
    }
#pragma unroll
    for (int ni = 0; ni < 2; ++ni) {
      f16x8 bh = *(const f16x8*)(sBh + (w2c * 2 + ni) * 512 + lane * 8);
      f16x8 bl = *(const f16x8*)(sBl + (w2c * 2 + ni) * 512 + lane * 8);
#pragma unroll
      for (int mi = 0; mi < 2; ++mi) {
        acc[mi][ni] = __builtin_amdgcn_mfma_f32_16x16x32_f16(ah[mi], bh, acc[mi][ni], 0, 0, 0);
        acc[mi][ni] = __builtin_amdgcn_mfma_f32_16x16x32_f16(al[mi], bh, acc[mi][ni], 0, 0, 0);
        acc[mi][ni] = __builtin_amdgcn_mfma_f32_16x16x32_f16(ah[mi], bl, acc[mi][ni], 0, 0, 0);
      }
    }
  };

  STAGE(0, 0);
#pragma unroll
  for (int kt = 0; kt < KT; ++kt) {
    if (kt + 1 < KT) {
      STAGE(kt + 1, (kt + 1) & 1);
      WAITVM4();
    } else {
      WAITVM0();
    }
    __builtin_amdgcn_s_barrier();
    COMPUTE(kt & 1);
    __builtin_amdgcn_s_barrier();
  }

#pragma unroll
  for (int ni = 0; ni < 2; ++ni) {
    int colL = (w2c * 2 + ni) * 16 + l16;
    float bv = bias[bn + colL];
#pragma unroll
    for (int mi = 0; mi < 2; ++mi) {
      int rowb = w2r * 32 + mi * 16 + g16 * 4;
#pragma unroll
      for (int r = 0; r < 4; ++r)
        sC[(rowb + r) * 68 + colL] = elu_f(acc[mi][ni][r] + bv);
    }
  }
  __syncthreads();
  const int bnT32 = bn >> 5;
#pragma unroll
  for (int s = 0; s < 2; ++s) {
    int chunkid = w * 2 + s;
    int msub = chunkid >> 1, ktl = chunkid & 1;
    int m = msub * 16 + l16;
    int cb = ktl * 32 + g16 * 8;
    f16x8 hv, lv;
#pragma unroll
    for (int j = 0; j < 8; ++j) {
      float v = sC[m * 68 + cb + j];
      _Float16 hh = (_Float16)v;
      hv[j] = hh;
      lv[j] = (_Float16)(v - (float)hh);
    }
    size_t gchunk = (size_t)(bmT + msub) * KT_NEXT + (bnT32 + ktl);
    *(f16x8*)((char*)Oh + gchunk * 1024 + lane * 16) = hv;
    *(f16x8*)((char*)Ol + gchunk * 1024 + lane * 16) = lv;
  }
}

// GNN reps, register-direct: 1 wave per 32x64 tile, grid (1564, 2).
// Output: interleaved reps_hl rows (512B = 4 kt-blocks of [h 64B | l 64B]).
__global__ __launch_bounds__(64) void reps_direct(
    const _Float16* __restrict__ xh, const _Float16* __restrict__ xl,
    const _Float16* __restrict__ xsah, const _Float16* __restrict__ xsal,
    const _Float16* __restrict__ xsoh, const _Float16* __restrict__ xsol,
    const _Float16* __restrict__ Wsh, const _Float16* __restrict__ Wsl,
    const float* __restrict__ bias,
    _Float16* __restrict__ Rhl) {
  __shared__ float sC[32][68];
  const int lane = threadIdx.x;
  const int mt = blockIdx.x, nt = blockIdx.y;
  const int bm = mt * 32, bn = nt * 64;
  const int l16 = lane & 15, g16 = lane >> 4;

  f32x4 acc1[2][4], acc2[2][4];
#pragma unroll
  for (int i = 0; i < 2; ++i)
#pragma unroll
    for (int j = 0; j < 4; ++j) acc1[i][j] = (f32x4)0.f;

  auto CP3 = [&](f32x4 (*acc)[4], const f16x8* ah, const f16x8* al,
                 const f16x8* bh, const f16x8* bl) {
#pragma unroll
    for (int ni = 0; ni < 4; ++ni)
#pragma unroll
      for (int mi = 0; mi < 2; ++mi) {
        acc[mi][ni] = __builtin_amdgcn_mfma_f32_16x16x32_f16(ah[mi], bh[ni], acc[mi][ni], 0, 0, 0);
        acc[mi][ni] = __builtin_amdgcn_mfma_f32_16x16x32_f16(al[mi], bh[ni], acc[mi][ni], 0, 0, 0);
        acc[mi][ni] = __builtin_amdgcn_mfma_f32_16x16x32_f16(ah[mi], bl[ni], acc[mi][ni], 0, 0, 0);
      }
  };

#pragma unroll
  for (int kt = 0; kt < 4; ++kt) {
    f16x8 ah[2], al[2], bh[4], bl[4];
#pragma unroll
    for (int mi = 0; mi < 2; ++mi) {
      size_t off = (size_t)(bm + mi * 16 + l16) * HD + kt * 32 + g16 * 8;
      ah[mi] = *(const f16x8*)(xh + off);
      al[mi] = *(const f16x8*)(xl + off);
    }
#pragma unroll
    for (int ni = 0; ni < 4; ++ni) {
      size_t ch = (size_t)kt * 8 + nt * 4 + ni;
      bh[ni] = *(const f16x8*)(Wsh + ch * 512 + lane * 8);
      bl[ni] = *(const f16x8*)(Wsl + ch * 512 + lane * 8);
    }
    CP3(acc1, ah, al, bh, bl);
  }
#pragma unroll
  for (int i = 0; i < 2; ++i)
#pragma unroll
    for (int j = 0; j < 4; ++j) acc2[i][j] = acc1[i][j];

#pragma unroll
  for (int kt = 0; kt < 4; ++kt) {
    f16x8 aah[2], aal[2], aoh[2], aol[2], bh[4], bl[4];
#pragma unroll
    for (int mi = 0; mi < 2; ++mi) {
      size_t off = (size_t)(bm + mi * 16 + l16) * HD + kt * 32 + g16 * 8;
      aah[mi] = *(const f16x8*)(xsah + off);
      aal[mi] = *(const f16x8*)(xsal + off);
      aoh[mi] = *(const f16x8*)(xsoh + off);
      aol[mi] = *(const f16x8*)(xsol + off);
    }
#pragma unroll
    for (int ni = 0; ni < 4; ++ni) {
      size_t ch = (size_t)(kt + 4) * 8 + nt * 4 + ni;
      bh[ni] = *(const f16x8*)(Wsh + ch * 512 + lane * 8);
      bl[ni] = *(const f16x8*)(Wsl + ch * 512 + lane * 8);
    }
    CP3(acc1, aah, aal, bh, bl);
    CP3(acc2, aoh, aol, bh, bl);
  }

#pragma unroll
  for (int ni = 0; ni < 4; ++ni) {
    int colL = ni * 16 + l16;
    float bv = bias[bn + colL];
#pragma unroll
    for (int mi = 0; mi < 2; ++mi) {
      int rowb = mi * 16 + g16 * 4;
#pragma unroll
      for (int r = 0; r < 4; ++r)
        sC[rowb + r][colL] = elu_f(acc1[mi][ni][r] + bv) - elu_f(acc2[mi][ni][r] + bv);
    }
  }
  __syncthreads();
#pragma unroll
  for (int c = 0; c < 4; ++c) {
    int msub = c >> 1, ktl = c & 1;
    int m = msub * 16 + l16;
    int cb = ktl * 32 + g16 * 8;
    int grow = bm + m;
    if (grow < NN) {
      f16x8 hv, lv;
#pragma unroll
      for (int j = 0; j < 8; ++j) {
        float v = sC[m][cb + j];
        _Float16 hh = (_Float16)v;
        hv[j] = hh;
        lv[j] = (_Float16)(v - (float)hh);
      }
      int ktg = (bn >> 5) + ktl;                 // global 32-col block index (0..3)
      size_t o = (size_t)grow * 256 + ktg * 64 + g16 * 8;
      *(f16x8*)(Rhl + o) = hv;
      *(f16x8*)(Rhl + o + 32) = lv;
    }
  }
}

// fused layer3+sel, 3-buffer counted-vmcnt: 4 waves, 64-row block. (verified r8-r13)
__global__ __launch_bounds__(256) void gemm3_sel(
    const _Float16* __restrict__ Ah, const _Float16* __restrict__ Al,
    const _Float16* __restrict__ Bh, const _Float16* __restrict__ Bl,
    const float* __restrict__ b34,
    const int* __restrict__ ei, const int* __restrict__ batchv, const int* __restrict__ yv,
    const float* __restrict__ Wp2, const float* __restrict__ bp2,
    float* __restrict__ sel, int* __restrict__ seg, int co) {
  __shared__ char smem[73728] __attribute__((aligned(16)));
  const int tid = threadIdx.x;
  const int w = tid >> 6, lane = tid & 63;
  const int l16 = lane & 15, g16 = lane >> 4;
  const int mt = blockIdx.x;

  f32x4 acc[8];
#pragma unroll
  for (int j = 0; j < 8; ++j) acc[j] = (f32x4)0.f;

  auto STAGE = [&](int kt, int buf) {
    char* base = smem + buf * 24576;
    size_t ch = (size_t)(mt * 4 + w) * 8 + kt;
    dma16((const char*)Ah + ch * 1024 + lane * 16, base + w * 1024);
    dma16((const char*)Al + ch * 1024 + lane * 16, base + 4096 + w * 1024);
#pragma unroll
    for (int s = 0; s < 2; ++s) {
      int nsub = w * 2 + s;
      size_t chb = (size_t)kt * 8 + nsub;
      dma16((const char*)Bh + chb * 1024 + lane * 16, base + 8192 + nsub * 1024);
      dma16((const char*)Bl + chb * 1024 + lane * 16, base + 16384 + nsub * 1024);
    }
  };

  auto COMPUTE = [&](int buf) {
    const _Float16* sAh = (const _Float16*)(smem + buf * 24576);
    const _Float16* sAl = (const _Float16*)(smem + buf * 24576 + 4096);
    const _Float16* sBh = (const _Float16*)(smem + buf * 24576 + 8192);
    const _Float16* sBl = (const _Float16*)(smem + buf * 24576 + 16384);
    f16x8 ah = *(const f16x8*)(sAh + w * 512 + lane * 8);
    f16x8 al = *(const f16x8*)(sAl + w * 512 + lane * 8);
#pragma unroll
    for (int ni = 0; ni < 8; ++ni) {
      f16x8 bh = *(const f16x8*)(sBh + ni * 512 + lane * 8);
      f16x8 bl = *(const f16x8*)(sBl + ni * 512 + lane * 8);
      acc[ni] = __builtin_amdgcn_mfma_f32_16x16x32_f16(ah, bh, acc[ni], 0, 0, 0);
      acc[ni] = __builtin_amdgcn_mfma_f32_16x16x32_f16(al, bh, acc[ni], 0, 0, 0);
      acc[ni] = __builtin_amdgcn_mfma_f32_16x16x32_f16(ah, bl, acc[ni], 0, 0, 0);
    }
  };

  STAGE(0, 0);
  STAGE(1, 1);
#pragma unroll
  for (int kt = 0; kt < 8; ++kt) {
    if (kt + 2 < 8) STAGE(kt + 2, (kt + 2) % 3);
    if (kt < 6) WAITVM12();
    else if (kt == 6) WAITVM6();
    else WAITVM0();
    __builtin_amdgcn_s_barrier();
    COMPUTE(kt % 3);
    __builtin_amdgcn_s_barrier();
  }

  float bb[8];
#pragma unroll
  for (int ni = 0; ni < 8; ++ni) bb[ni] = b34[ni * 16 + l16];

#pragma unroll
  for (int rr = 0; rr < 4; ++rr) {
    int row = w * 16 + g16 * 4 + rr;
    int e = co + mt * 64 + row;
    int s = ei[NOCP + e];
    int gg = batchv[s];
    int c = yv[gg];
    float a = 0.f;
#pragma unroll
    for (int ni = 0; ni < 8; ++ni)
      a += elu_f(acc[ni][rr] + bb[ni]) * Wp2[(ni * 16 + l16) * 10 + c];
    a += __shfl_xor(a, 1);
    a += __shfl_xor(a, 2);
    a += __shfl_xor(a, 4);
    a += __shfl_xor(a, 8);
    if (l16 == 0) { sel[e] = a + bp2[c]; seg[e] = gg; }
  }
}

// ---------------- tail: segment softmax/argmax ----------------
__global__ __launch_bounds__(256) void segmax_sel(const float* __restrict__ sel,
    const int* __restrict__ seg, unsigned* __restrict__ mx_enc) {
  __shared__ unsigned sm[NG];
  int tid = threadIdx.x;
  if (tid < NG) sm[tid] = 0u;
  __syncthreads();
  for (int i = blockIdx.x * blockDim.x + tid; i < EAVA; i += gridDim.x * blockDim.x)
    atomicMax(&sm[seg[i]], fenc(sel[i]));
  __syncthreads();
  if (tid < NG) atomicMax(&mx_enc[tid], sm[tid]);
}

__global__ __launch_bounds__(256) void exden_kernel(const float* __restrict__ sel,
    const int* __restrict__ seg, const unsigned* __restrict__ mx_enc,
    float* __restrict__ denom, float* __restrict__ out_probs) {
  __shared__ float sd[NG];
  __shared__ float smx[NG];
  int tid = threadIdx.x;
  if (tid < NG) { smx[tid] = fdec(mx_enc[tid]); sd[tid] = 0.f; }
  __syncthreads();
  for (int i = blockIdx.x * blockDim.x + tid; i < EAVA; i += gridDim.x * blockDim.x) {
    int g = seg[i];
    float ex = expf(sel[i] - smx[g]);
    out_probs[i] = ex;
    atomicAdd(&sd[g], ex);
  }
  __syncthreads();
  if (tid < NG) atomicAdd(&denom[tid], sd[tid]);
}

__global__ __launch_bounds__(256) void probpmax_kernel(const int* __restrict__ seg,
    const float* __restrict__ denom, float* __restrict__ out_probs,
    unsigned* __restrict__ pmax_enc) {
  __shared__ float sden[NG];
  __shared__ unsigned sp[NG];
  int tid = threadIdx.x;
  if (tid < NG) { sden[tid] = denom[tid]; sp[tid] = 0u; }
  __syncthreads();
  for (int i = blockIdx.x * blockDim.x + tid; i < EAVA; i += gridDim.x * blockDim.x) {
    int g = seg[i];
    float p = out_probs[i] / sden[g];
    out_probs[i] = p;
    atomicMax(&sp[g], fenc(p));
  }
  __syncthreads();
  if (tid < NG) atomicMax(&pmax_enc[tid], sp[tid]);
}

__global__ __launch_bounds__(256) void argmin_kernel(const int* __restrict__ seg,
    const float* __restrict__ out_probs, const unsigned* __restrict__ pmax_enc,
    int* __restrict__ amin) {
  __shared__ float spm[NG];
  __shared__ int sa[NG];
  int tid = threadIdx.x;
  if (tid < NG) { spm[tid] = fdec(pmax_enc[tid]); sa[tid] = EAVA; }
  __syncthreads();
  for (int i = blockIdx.x * blockDim.x + tid; i < EAVA; i += gridDim.x * blockDim.x) {
    int g = seg[i];
    if (out_probs[i] == spm[g]) atomicMin(&sa[g], i);
  }
  __syncthreads();
  if (tid < NG) atomicMin(&amin[tid], sa[tid]);
}

__global__ void finalize_kernel(const unsigned* __restrict__ pmax_enc,
    const int* __restrict__ amin, float* __restrict__ out) {
  int g = threadIdx.x;
  if (g < NG) {
    out[EAVA + g] = fdec(pmax_enc[g]);
    out[EAVA + NG + g] = (float)amin[g];
  }
}

extern "C" void kernel_launch(void* const* d_in, const int* in_sizes, int n_in,
                              void* d_out, int out_size, void* d_ws, size_t ws_size,
                              hipStream_t stream) {
  const float* x      = (const float*)d_in[0];
  const int*   ei     = (const int*)d_in[1];
  const int*   batchv = (const int*)d_in[2];
  const int*   yv     = (const int*)d_in[3];
  const float* Wself = (const float*)d_in[5];
  const float* Wnbr  = (const float*)d_in[6];
  const float* bgnn  = (const float*)d_in[7];
  const float* Wr1   = (const float*)d_in[8];
  const float* br1   = (const float*)d_in[9];
  const float* Wr2   = (const float*)d_in[10];
  const float* br2   = (const float*)d_in[11];
  const float* Wr3   = (const float*)d_in[12];
  const float* br3   = (const float*)d_in[13];
  const float* Wp1   = (const float*)d_in[14];
  const float* bp1   = (const float*)d_in[15];
  const float* Wp2   = (const float*)d_in[16];
  const float* bp2   = (const float*)d_in[17];
  float* out = (float*)d_out;

  char* wp = (char*)d_ws;
  auto alloc = [&](size_t bytes) -> char* {
    char* p = wp;
    wp += (bytes + 255) & ~(size_t)255;
    return p;
  };
  // 6 contiguous split arrays (padded to NNP rows): xh, xl, xsah, xsal, xsoh, xsol
  _Float16* xsplit = (_Float16*)alloc((size_t)6 * NNP * HD * 2);
  _Float16* xh   = xsplit + (size_t)0 * NNP * HD;
  _Float16* xl   = xsplit + (size_t)1 * NNP * HD;
  _Float16* xsah = xsplit + (size_t)2 * NNP * HD;
  _Float16* xsal = xsplit + (size_t)3 * NNP * HD;
  _Float16* xsoh = xsplit + (size_t)4 * NNP * HD;
  _Float16* xsol = xsplit + (size_t)5 * NNP * HD;
  _Float16*  reps_hl  = (_Float16*)alloc((size_t)NN * 256 * 2);   // interleaved h/l rows
  int*       cnt      = (int*)alloc((size_t)NN * 4);
  int*       bucket   = (int*)alloc((size_t)NN * CAP * 4);
  float*     sel      = (float*)alloc((size_t)EAVA * 4);
  int*       seg      = (int*)alloc((size_t)EAVA * 4);
  unsigned*  mx_enc   = (unsigned*)alloc(NG * 4);
  float*     denom    = (float*)alloc(NG * 4);
  unsigned*  pmax_enc = (unsigned*)alloc(NG * 4);
  int*       amin     = (int*)alloc(NG * 4);
  // packed weights (hi/lo)
  _Float16*  Wsh  = (_Float16*)alloc((size_t)64 * 1024);   // [Wself;Wnbr] 8kt x 8ns
  _Float16*  Wsl  = (_Float16*)alloc((size_t)64 * 1024);
  _Float16*  Wr1h = (_Float16*)alloc((size_t)8 * 32 * 1024);
  _Float16*  Wr1l = (_Float16*)alloc((size_t)8 * 32 * 1024);
  _Float16*  Wr2h = (_Float16*)alloc((size_t)16 * 16 * 1024);
  _Float16*  Wr2l = (_Float16*)alloc((size_t)16 * 16 * 1024);
  float*     W34  = (float*)alloc((size_t)256 * 128 * 4);
  float*     b34  = (float*)alloc(128 * 4);
  _Float16*  W34h = (_Float16*)alloc((size_t)8 * 8 * 1024);
  _Float16*  W34l = (_Float16*)alloc((size_t)8 * 8 * 1024);
  // per-chunk activation pack buffers
  _Float16*  b1h = (_Float16*)alloc((size_t)(CHNK / 16) * 16 * 1024);
  _Float16*  b1l = (_Float16*)alloc((size_t)(CHNK / 16) * 16 * 1024);
  _Float16*  b2h = (_Float16*)alloc((size_t)(CHNK / 16) * 8 * 1024);
  _Float16*  b2l = (_Float16*)alloc((size_t)(CHNK / 16) * 8 * 1024);
  (void)ws_size;

  // ---- prep ----
  zero_i<<<64, 256, 0, stream>>>(cnt, NN);
  init_small<<<1, 64, 0, stream>>>(mx_enc, denom, pmax_enc, amin);
  zero_tails<<<18, 256, 0, stream>>>(xsplit);
  bucket_kernel<<<NE / 256, 256, 0, stream>>>(ei, cnt, bucket);
  gather_kernel<<<(NN + 3) / 4, 256, 0, stream>>>(x, cnt, bucket, xsah, xsal, xsoh, xsol);
  split_x<<<(NN * HD / 8 + 255) / 256, 256, 0, stream>>>(x, xh, xl);
  pack_w2<<<64, 64, 0, stream>>>(Wself, Wnbr, Wsh, Wsl);
  reps_direct<<<dim3(NNP / 32, 2), 64, 0, stream>>>(xh, xl, xsah, xsal, xsoh, xsol, Wsh, Wsl,
                                                    bgnn, reps_hl);
  w34_kernel<<<256, 128, 0, stream>>>(Wr3, Wp1, br3, bp1, W34, b34);
  pack_w<<<8 * 32, 64, 0, stream>>>(Wr1, 256, 512, Wr1h, Wr1l);
  pack_w<<<16 * 16, 64, 0, stream>>>(Wr2, 512, 256, Wr2h, Wr2l);
  pack_w<<<8 * 8, 64, 0, stream>>>(W34, 256, 128, W34h, W34l);

  // ---- per-edge MLP: 7 chunks of 32768 ----
  for (int c = 0; c < 7; ++c) {
    int co = c * CHNK;
    gemm1_il<8><<<(CHNK / 64) * 8, 256, 0, stream>>>(
        reps_hl, ei + NOCP + co, ei + NE + NOCP + co, Wr1h, Wr1l, br1, b1h, b1l);
    gemm_ab<16, 16, 8, 4><<<(CHNK / 64) * 4, 256, 0, stream>>>(
        b1h, b1l, Wr2h, Wr2l, br2, b2h, b2l);
    gemm3_sel<<<CHNK / 64, 256, 0, stream>>>(
        b2h, b2l, W34h, W34l, b34, ei, batchv, yv, Wp2, bp2, sel, seg, co);
  }

  // ---- segment softmax + argmax ----
  segmax_sel<<<112, 256, 0, stream>>>(sel, seg, mx_enc);
  exden_kernel<<<112, 256, 0, stream>>>(sel, seg, mx_enc, denom, out);
  probpmax_kernel<<<112, 256, 0, stream>>>(seg, denom, out, pmax_enc);
  argmin_kernel<<<112, 256, 0, stream>>>(seg, out, pmax_enc, amin);
  finalize_kernel<<<1, 64, 0, stream>>>(pmax_enc, amin, out);
}